// Round 10
// baseline (1235.611 us; speedup 1.0000x reference)
//
#include <hip/hip_runtime.h>

static const int kN = 50000;   // nodes
static const int kE = 300000;  // edges
static const int kG = 2048;    // graphs
static const int kT = 19;      // targets
static const int kSeg = kN * 4;  // CSR segments: key = dst*4 + rel
static const int kScanB = (kSeg + 256) / 256;  // 784 blocks covers kSeg+1

typedef __bf16 bf16;
typedef __bf16 bf16x8 __attribute__((ext_vector_type(8)));
typedef __bf16 bf16x4 __attribute__((ext_vector_type(4)));
typedef float  f32x4  __attribute__((ext_vector_type(4)));

// ---------------------------------------------------------------------------
// GEMM1 layers 2/3: aggregate (CSR, +self) into LDS, then MFMA vs w1t[r].
// Grid (ceil(N/64), 4=rel), 512 threads (8 waves). Proven round-9 shape.
// Layouts (m89/m91-verified): A/B idx=lane&15,k=(lane>>4)*8+j;
//                             C/D row=(lane>>4)*4+reg, col=lane&15.
// ---------------------------------------------------------------------------
__global__ __launch_bounds__(512) void k_rgin1(
    const bf16* __restrict__ Pb, const int* __restrict__ srcidx,
    const int* __restrict__ row_ptr, const bf16* __restrict__ w1t,
    bf16* __restrict__ h1, float* __restrict__ stats)
{
    __shared__ bf16 As[64][264];   // row stride 264 bf16 = 132 dwords
    const int t = threadIdx.x;
    const int r = blockIdx.y;
    const int m0 = blockIdx.x * 64;
    const int wave = t >> 6, lane = t & 63;
    const int l15 = lane & 15, lq = lane >> 4, koff = lq * 8;
    const int wn = wave * 32;

    // B pointers + first-fragment prefetch (lands during phase 1)
    const bf16* Bt = w1t + (long)r * 65536;
    const bf16* Bp[2];
#pragma unroll
    for (int j = 0; j < 2; ++j)
        Bp[j] = Bt + (long)(wn + j * 16 + l15) * 256 + koff;
    bf16x8 b0[2], b1[2];
#pragma unroll
    for (int j = 0; j < 2; ++j) b0[j] = *(const bf16x8*)(Bp[j]);

    // ---- phase 1: 8 rows per wave, headers preloaded ----
    {
        const int rbase = m0 + wave * 8;
        int i0s[8], i1s[8];
#pragma unroll
        for (int rr = 0; rr < 8; ++rr) {
            int dc = rbase + rr; if (dc >= kN) dc = kN - 1;
            int seg = dc * 4 + r;
            i0s[rr] = row_ptr[seg];
            i1s[rr] = row_ptr[seg + 1];
        }
#pragma unroll
        for (int rr = 0; rr < 8; ++rr) {
            int dc = rbase + rr; if (dc >= kN) dc = kN - 1;
            bf16x4 sv = ((const bf16x4*)(Pb + (long)dc * 256))[lane];
            f32x4 a = {(float)sv[0], (float)sv[1], (float)sv[2], (float)sv[3]};
            int i = i0s[rr], i1 = i1s[rr];
            for (; i + 1 < i1; i += 2) {
                int s0 = srcidx[i], s1 = srcidx[i + 1];
                bf16x4 v0 = ((const bf16x4*)(Pb + (long)s0 * 256))[lane];
                bf16x4 v1 = ((const bf16x4*)(Pb + (long)s1 * 256))[lane];
                a[0] += (float)v0[0] + (float)v1[0];
                a[1] += (float)v0[1] + (float)v1[1];
                a[2] += (float)v0[2] + (float)v1[2];
                a[3] += (float)v0[3] + (float)v1[3];
            }
            if (i < i1) {
                bf16x4 v0 = ((const bf16x4*)(Pb + (long)srcidx[i] * 256))[lane];
                a[0] += (float)v0[0]; a[1] += (float)v0[1];
                a[2] += (float)v0[2]; a[3] += (float)v0[3];
            }
            bf16x4 o = {(bf16)a[0], (bf16)a[1], (bf16)a[2], (bf16)a[3]};
            *(bf16x4*)&As[wave * 8 + rr][lane * 4] = o;
        }
    }
    __syncthreads();

    // ---- phase 2: MFMA from LDS, B double-buffered in regs ----
    const bf16* Ar[4];
#pragma unroll
    for (int i = 0; i < 4; ++i) Ar[i] = &As[i * 16 + l15][koff];

    f32x4 acc[4][2];
#pragma unroll
    for (int i = 0; i < 4; ++i)
#pragma unroll
        for (int j = 0; j < 2; ++j) acc[i][j] = (f32x4){0.f, 0.f, 0.f, 0.f};

#pragma unroll
    for (int kt = 0; kt < 256; kt += 32) {
        int kn = kt + 32; if (kn >= 256) kn = 0;
#pragma unroll
        for (int j = 0; j < 2; ++j) b1[j] = *(const bf16x8*)(Bp[j] + kn);
        bf16x8 a[4];
#pragma unroll
        for (int i = 0; i < 4; ++i) a[i] = *(const bf16x8*)(Ar[i] + kt);
#pragma unroll
        for (int i = 0; i < 4; ++i)
#pragma unroll
            for (int j = 0; j < 2; ++j)
                acc[i][j] = __builtin_amdgcn_mfma_f32_16x16x32_bf16(a[i], b0[j], acc[i][j], 0, 0, 0);
#pragma unroll
        for (int j = 0; j < 2; ++j) b0[j] = b1[j];
    }

    // ---- epilogue: store h1 + fused stats ----
    const int cB = r * 256;
    float sv[2] = {0, 0}, qv[2] = {0, 0};
#pragma unroll
    for (int i = 0; i < 4; ++i) {
        int rowb = m0 + i * 16 + lq * 4;
#pragma unroll
        for (int rr = 0; rr < 4; ++rr) {
            int gm = rowb + rr;
            if (gm < kN) {
#pragma unroll
                for (int j = 0; j < 2; ++j) {
                    int gn = wn + j * 16 + l15;
                    bf16 bv = (bf16)acc[i][j][rr];
                    h1[(long)gm * 1024 + cB + gn] = bv;
                    float f = (float)bv;
                    sv[j] += f; qv[j] += f * f;
                }
            }
        }
    }
#pragma unroll
    for (int j = 0; j < 2; ++j) {
        float s = sv[j], q = qv[j];
        s += __shfl_xor(s, 16); s += __shfl_xor(s, 32);
        q += __shfl_xor(q, 16); q += __shfl_xor(q, 32);
        if (lq == 0) {
            int gn = cB + wn + j * 16 + l15;
            atomicAdd(&stats[gn], s);
            atomicAdd(&stats[1024 + gn], q);
        }
    }
}

// ---------------------------------------------------------------------------
// GEMM1 layer 1: A = a1b[r] [N,32] bf16 (K=32, one MFMA step) + fused stats.
// ---------------------------------------------------------------------------
__global__ __launch_bounds__(512) void k_l1gemm(
    const bf16* __restrict__ a1b, const bf16* __restrict__ w1tL1,
    bf16* __restrict__ h1, float* __restrict__ stats)
{
    const int t = threadIdx.x;
    const int r = blockIdx.y;
    const int m0 = blockIdx.x * 128;
    const int wave = t >> 6, lane = t & 63;
    const int l15 = lane & 15, lq = lane >> 4, koff = lq * 8;
    const int wm = (wave & 1) * 64, wn = (wave >> 1) * 64;

    bf16x8 a[4], b[4];
#pragma unroll
    for (int i = 0; i < 4; ++i) {
        int gm = m0 + wm + i * 16 + l15;
        if (gm >= kN) gm = kN - 1;
        a[i] = *(const bf16x8*)(a1b + ((long)r * kN + gm) * 32 + koff);
    }
#pragma unroll
    for (int j = 0; j < 4; ++j)
        b[j] = *(const bf16x8*)(w1tL1 + (long)r * 8192 + (long)(wn + j * 16 + l15) * 32 + koff);

    f32x4 acc[4][4];
#pragma unroll
    for (int i = 0; i < 4; ++i)
#pragma unroll
        for (int j = 0; j < 4; ++j)
            acc[i][j] = __builtin_amdgcn_mfma_f32_16x16x32_bf16(a[i], b[j],
                        (f32x4){0.f, 0.f, 0.f, 0.f}, 0, 0, 0);

    const int cB = r * 256;
    float sv[4] = {0,0,0,0}, qv[4] = {0,0,0,0};
#pragma unroll
    for (int i = 0; i < 4; ++i) {
        int rowb = m0 + wm + i * 16 + lq * 4;
#pragma unroll
        for (int rr = 0; rr < 4; ++rr) {
            int gm = rowb + rr;
            if (gm < kN) {
#pragma unroll
                for (int j = 0; j < 4; ++j) {
                    int gn = wn + j * 16 + l15;
                    bf16 bv = (bf16)acc[i][j][rr];
                    h1[(long)gm * 1024 + cB + gn] = bv;
                    float f = (float)bv;
                    sv[j] += f; qv[j] += f * f;
                }
            }
        }
    }
#pragma unroll
    for (int j = 0; j < 4; ++j) {
        float s = sv[j], q = qv[j];
        s += __shfl_xor(s, 16); s += __shfl_xor(s, 32);
        q += __shfl_xor(q, 16); q += __shfl_xor(q, 32);
        if (lq == 0) {
            int gn = cB + wn + j * 16 + l15;
            atomicAdd(&stats[gn], s);
            atomicAdd(&stats[1024 + gn], q);
        }
    }
}

// ---------------------------------------------------------------------------
// GEMM2 v4 (rgin1-shaped): C = relu( [A1 | relu(BN(A2))] @ Bt^T + bias ).
// K = 1280 for ALL layers (layer-1 x padded to 256). A1:[M,256] chunk 0;
// A2 = h1 [M,1024] chunks 1..4 (BN at staging). 512 thr (8 waves, 2m x 4n),
// M-tile 64, K-chunk 256 in single LDS tile As[64][264]; per chunk:
// next-chunk A reg-prefetch issued before an 8-kstep statically-unrolled
// MFMA burst (64 MFMA/wave between barriers); B depth-2 reg prefetch.
// PoolOut: atomicAdd rows into pooled[batch].
// ---------------------------------------------------------------------------
template<bool PoolOut>
__global__ __launch_bounds__(512) void k_gemm2(
    const bf16* __restrict__ A1,
    const bf16* __restrict__ A2,
    const bf16* __restrict__ Bt,
    bf16* __restrict__ Cout,
    int M, const float* __restrict__ bias,
    const float* __restrict__ scl, const float* __restrict__ shf,
    const int* __restrict__ batch, float* __restrict__ pooled)
{
    constexpr int K = 1280;
    __shared__ bf16 As[64][264];
    const int t = threadIdx.x;
    const int wave = t >> 6, lane = t & 63;
    const int l15 = lane & 15, lq = lane >> 4, koff = lq * 8;
    const int wm = (wave & 1) * 32;
    const int wn = (wave >> 1) * 64;
    const int m0 = blockIdx.x * 64;

    // staging: thread t handles rows (t>>5)+u*16 (u=0..3), col group (t&31)*8
    const int srow = t >> 5;
    const int c8   = (t & 31) * 8;

    const bf16* Bp[4];
#pragma unroll
    for (int j = 0; j < 4; ++j)
        Bp[j] = Bt + (long)(wn + j * 16 + l15) * K + koff;

    f32x4 acc[2][4];
#pragma unroll
    for (int i = 0; i < 2; ++i)
#pragma unroll
        for (int j = 0; j < 4; ++j) acc[i][j] = (f32x4){0.f, 0.f, 0.f, 0.f};

    auto ld_raw = [&](int c, bf16x8* rv, float4* sf) {
#pragma unroll
        for (int u = 0; u < 4; ++u) {
            int gm = m0 + srow + u * 16; if (gm >= M) gm = M - 1;
            if (c == 0) rv[u] = *(const bf16x8*)(A1 + (long)gm * 256 + c8);
            else        rv[u] = *(const bf16x8*)(A2 + (long)gm * 1024 + (c - 1) * 256 + c8);
        }
        if (c > 0) {
            int k2 = (c - 1) * 256 + c8;
            sf[0] = *(const float4*)(scl + k2);
            sf[1] = *(const float4*)(scl + k2 + 4);
            sf[2] = *(const float4*)(shf + k2);
            sf[3] = *(const float4*)(shf + k2 + 4);
        }
    };
    auto st_lds = [&](int c, const bf16x8* rv, const float4* sf) {
        float sa[8], ta[8];
        if (c > 0) {
            sa[0]=sf[0].x; sa[1]=sf[0].y; sa[2]=sf[0].z; sa[3]=sf[0].w;
            sa[4]=sf[1].x; sa[5]=sf[1].y; sa[6]=sf[1].z; sa[7]=sf[1].w;
            ta[0]=sf[2].x; ta[1]=sf[2].y; ta[2]=sf[2].z; ta[3]=sf[2].w;
            ta[4]=sf[3].x; ta[5]=sf[3].y; ta[6]=sf[3].z; ta[7]=sf[3].w;
        }
#pragma unroll
        for (int u = 0; u < 4; ++u) {
            bf16x8 v = rv[u];
            if (c > 0) {
                bf16x8 o;
#pragma unroll
                for (int w = 0; w < 8; ++w)
                    o[w] = (bf16)fmaxf(0.f, fmaf((float)v[w], sa[w], ta[w]));
                v = o;
            }
            *(bf16x8*)&As[srow + u * 16][c8] = v;
        }
    };

    // prologue: stage chunk 0, prime B depth-2
    bf16x8 rv[4]; float4 sf[4];
    ld_raw(0, rv, sf);
    bf16x8 breg[2][4];
#pragma unroll
    for (int j = 0; j < 4; ++j) breg[0][j] = *(const bf16x8*)(Bp[j]);
#pragma unroll
    for (int j = 0; j < 4; ++j) breg[1][j] = *(const bf16x8*)(Bp[j] + 32);
    st_lds(0, rv, sf);
    __syncthreads();

    for (int c = 0; c < 5; ++c) {
        if (c + 1 < 5) ld_raw(c + 1, rv, sf);   // global loads fly over MFMA burst
#pragma unroll
        for (int ks = 0; ks < 8; ++ks) {
            bf16x8 a[2], bu[4];
#pragma unroll
            for (int i = 0; i < 2; ++i)
                a[i] = *(const bf16x8*)&As[wm + i * 16 + l15][ks * 32 + koff];
#pragma unroll
            for (int j = 0; j < 4; ++j) bu[j] = breg[ks & 1][j];
            int knext = c * 256 + (ks + 2) * 32; if (knext >= K) knext = 0;
#pragma unroll
            for (int j = 0; j < 4; ++j) breg[ks & 1][j] = *(const bf16x8*)(Bp[j] + knext);
#pragma unroll
            for (int i = 0; i < 2; ++i)
#pragma unroll
                for (int j = 0; j < 4; ++j)
                    acc[i][j] = __builtin_amdgcn_mfma_f32_16x16x32_bf16(a[i], bu[j], acc[i][j], 0, 0, 0);
        }
        if (c + 1 < 5) {
            __syncthreads();        // all waves' LDS reads of chunk c done
            st_lds(c + 1, rv, sf);
            __syncthreads();        // new tile visible
        }
    }

#pragma unroll
    for (int i = 0; i < 2; ++i) {
        int rowb = m0 + wm + i * 16 + lq * 4;
#pragma unroll
        for (int rr = 0; rr < 4; ++rr) {
            int gm = rowb + rr;
            if (gm < M) {
                int g = PoolOut ? batch[gm] : 0;
#pragma unroll
                for (int j = 0; j < 4; ++j) {
                    int gn = wn + j * 16 + l15;
                    float v = fmaxf(acc[i][j][rr] + bias[gn], 0.f);
                    if (PoolOut) atomicAdd(&pooled[(long)g * 256 + gn], v);
                    else         Cout[(long)gm * 256 + gn] = (bf16)v;
                }
            }
        }
    }
}

// ---------------------------------------------------------------------------
// CSR build
__global__ void k_hist(const int* __restrict__ ei, const int* __restrict__ et,
                       int* __restrict__ hist)
{
    int e = blockIdx.x * 256 + threadIdx.x;
    if (e >= kE) return;
    atomicAdd(&hist[ei[kE + e] * 4 + et[e]], 1);
}

__global__ void k_scan1(const int* __restrict__ hist, int* __restrict__ bsum)
{
    __shared__ int sd[256];
    int i = blockIdx.x * 256 + threadIdx.x;
    sd[threadIdx.x] = (i < kSeg) ? hist[i] : 0;
    __syncthreads();
    for (int o = 128; o > 0; o >>= 1) {
        if (threadIdx.x < o) sd[threadIdx.x] += sd[threadIdx.x + o];
        __syncthreads();
    }
    if (threadIdx.x == 0) bsum[blockIdx.x] = sd[0];
}

__global__ __launch_bounds__(1024) void k_scan2(const int* __restrict__ bsum,
                                                int* __restrict__ boff)
{
    __shared__ int sd[1024];
    int t = threadIdx.x;
    sd[t] = (t < kScanB) ? bsum[t] : 0;
    __syncthreads();
    for (int o = 1; o < 1024; o <<= 1) {
        int v = (t >= o) ? sd[t - o] : 0;
        __syncthreads();
        sd[t] += v;
        __syncthreads();
    }
    if (t < kScanB) boff[t] = (t == 0) ? 0 : sd[t - 1];
}

__global__ void k_scan3(const int* __restrict__ hist, const int* __restrict__ boff,
                        int* __restrict__ row_ptr, int* __restrict__ cursor)
{
    __shared__ int sd[256];
    int i = blockIdx.x * 256 + threadIdx.x;
    int v = (i < kSeg) ? hist[i] : 0;
    sd[threadIdx.x] = v;
    __syncthreads();
    for (int o = 1; o < 256; o <<= 1) {
        int u = (threadIdx.x >= o) ? sd[threadIdx.x - o] : 0;
        __syncthreads();
        sd[threadIdx.x] += u;
        __syncthreads();
    }
    if (i <= kSeg) {
        int excl = boff[blockIdx.x] + sd[threadIdx.x] - v;
        row_ptr[i] = excl;
        if (i < kSeg) cursor[i] = excl;
    }
}

__global__ void k_fill(const int* __restrict__ ei, const int* __restrict__ et,
                       int* __restrict__ cursor, int* __restrict__ srcidx)
{
    int e = blockIdx.x * 256 + threadIdx.x;
    if (e >= kE) return;
    int key = ei[kE + e] * 4 + et[e];
    int pos = atomicAdd(&cursor[key], 1);
    srcidx[pos] = ei[e];
}

// ---------------------------------------------------------------------------
// layer-1 aggregate: a1b[r][d][ch] = bf16( x[d][ch] + sum_src x[src][ch] ), ch<11
__global__ void k_agg11(const float* __restrict__ x, const int* __restrict__ srcidx,
                        const int* __restrict__ row_ptr, bf16* __restrict__ a1b)
{
    long gid = (long)blockIdx.x * 256 + threadIdx.x;
    if (gid >= (long)kSeg * 32) return;
    int ch  = (int)(gid & 31);
    int seg = (int)(gid >> 5);
    int d = seg >> 2, r = seg & 3;
    float acc = 0.f;
    if (ch < 11) {
        acc = x[(long)d * 11 + ch];
        int i0 = row_ptr[seg], i1 = row_ptr[seg + 1];
        for (int i = i0; i < i1; ++i) acc += x[(long)srcidx[i] * 11 + ch];
    }
    a1b[((long)r * kN + d) * 32 + ch] = (bf16)acc;
}

// x [N,11] fp32 -> xb1 [N,256] bf16 zero-padded (chunk 0 of unified K=1280)
__global__ void k_xpad(const float* __restrict__ x, bf16* __restrict__ xb1)
{
    long gid = (long)blockIdx.x * 256 + threadIdx.x;
    if (gid >= (long)kN * 256) return;
    int c = (int)(gid & 255); long d = gid >> 8;
    xb1[gid] = (c < 11) ? (bf16)x[d * 11 + c] : (bf16)0.f;
}

// weight transpose-pack: in [K,N] fp32 -> out[n*ldout + coff + k] bf16
__global__ void k_wt_s(const float* __restrict__ in, bf16* __restrict__ out,
                       int K, int N, int ldout, int coff)
{
    int i = blockIdx.x * 256 + threadIdx.x;
    if (i >= K * N) return;
    int n = i / K, k = i - n * K;
    out[(long)n * ldout + coff + k] = (bf16)in[(long)k * N + n];
}

// layer-1 w1 pack: [4][11][256] fp32 -> [4][256][32] bf16 zero-padded
__global__ void k_wtL1(const float* __restrict__ w1, bf16* __restrict__ out)
{
    int i = blockIdx.x * 256 + threadIdx.x;
    if (i >= 4 * 256 * 32) return;
    int r = i >> 13, rem = i & 8191, n = rem >> 5, k = rem & 31;
    out[i] = (k < 11) ? (bf16)w1[(long)r * 11 * 256 + (long)k * 256 + n] : (bf16)0.f;
}

__global__ void k_bn_params(const float* __restrict__ stats,
                            const float* __restrict__ g, const float* __restrict__ bt,
                            float* __restrict__ scl, float* __restrict__ shf)
{
    int c = blockIdx.x * 256 + threadIdx.x;  // < 1024
    const float invN = 1.0f / (float)kN;
    float mu  = stats[c] * invN;
    float var = stats[1024 + c] * invN - mu * mu;
    float sc  = g[c] * rsqrtf(var + 1e-5f);
    scl[c] = sc;
    shf[c] = bt[c] - mu * sc;
}

__global__ void k_bias_total(const float* sb0, const float* b20,
                             const float* sb1, const float* b21,
                             const float* sb2, const float* b22,
                             float* __restrict__ btt)
{
    int l = blockIdx.x, j = threadIdx.x;
    const float* sb = (l == 0) ? sb0 : (l == 1) ? sb1 : sb2;
    const float* b2 = (l == 0) ? b20 : (l == 1) ? b21 : b22;
    float v = sb[j];
#pragma unroll
    for (int r = 0; r < 4; ++r) v += b2[r * 256 + j];
    btt[l * 256 + j] = v;
}

__global__ void k_counts(const int* __restrict__ batch, float* __restrict__ counts)
{
    int v = blockIdx.x * 256 + threadIdx.x;
    if (v < kN) atomicAdd(&counts[batch[v]], 1.0f);
}

__global__ __launch_bounds__(64) void k_head(const float* __restrict__ pooled,
                                             const float* __restrict__ counts,
                                             const float* __restrict__ lw,
                                             const float* __restrict__ lb,
                                             float* __restrict__ out)
{
    int g = blockIdx.x;
    int l = threadIdx.x;
    float inv = 1.0f / fmaxf(counts[g], 1.0f);
    float acc[kT];
#pragma unroll
    for (int t = 0; t < kT; ++t) acc[t] = 0.f;
    for (int k = l; k < 256; k += 64) {
        float p = pooled[((long)g << 8) + k] * inv;
#pragma unroll
        for (int t = 0; t < kT; ++t) acc[t] = fmaf(p, lw[k * kT + t], acc[t]);
    }
#pragma unroll
    for (int off = 32; off > 0; off >>= 1)
#pragma unroll
        for (int t = 0; t < kT; ++t) acc[t] += __shfl_down(acc[t], off);
    if (l == 0) {
#pragma unroll
        for (int t = 0; t < kT; ++t) out[(long)g * kT + t] = acc[t] + lb[t];
    }
}

// ---------------------------------------------------------------------------
extern "C" void kernel_launch(void* const* d_in, const int* in_sizes, int n_in,
                              void* d_out, int out_size, void* d_ws, size_t ws_size,
                              hipStream_t stream)
{
    const float* x     = (const float*)d_in[0];
    const int*   ei    = (const int*)d_in[1];
    const int*   et    = (const int*)d_in[2];
    const int*   batch = (const int*)d_in[3];

    const float *sw[3], *sb[3], *w1[3], *gmm[3], *btm[3], *w2[3], *b2[3];
    for (int l = 0; l < 3; ++l) {
        int b = 4 + l * 8;
        sw[l]  = (const float*)d_in[b + 0];
        sb[l]  = (const float*)d_in[b + 1];
        w1[l]  = (const float*)d_in[b + 2];
        // b+3 = b1 (cancels inside BatchNorm)
        gmm[l] = (const float*)d_in[b + 4];
        btm[l] = (const float*)d_in[b + 5];
        w2[l]  = (const float*)d_in[b + 6];
        b2[l]  = (const float*)d_in[b + 7];
    }
    const float* lin_w = (const float*)d_in[28];
    const float* lin_b = (const float*)d_in[29];
    float* out = (float*)d_out;
    (void)in_sizes; (void)n_in; (void)out_size;

    // ---- workspace (~200 MB) ----
    char* wsb = (char*)d_ws;
    size_t off = 0;
    auto alloc = [&](size_t bytes) { void* p = wsb + off; off = (off + bytes + 255) & ~(size_t)255; return p; };
    bf16*  Pb0    = (bf16*) alloc((size_t)kN * 256 * 2);
    bf16*  Pb1    = (bf16*) alloc((size_t)kN * 256 * 2);
    bf16*  h1     = (bf16*) alloc((size_t)kN * 1024 * 2);
    bf16*  a1b    = (bf16*) alloc((size_t)4 * kN * 32 * 2);
    bf16*  xb1    = (bf16*) alloc((size_t)kN * 256 * 2);        // padded to 256
    bf16*  w1t    = (bf16*) alloc((size_t)2 * 4 * 65536 * 2);   // layers 2,3
    bf16*  w1tL1  = (bf16*) alloc((size_t)4 * 256 * 32 * 2);
    bf16*  Bc0    = (bf16*) alloc((size_t)256 * 1280 * 2);      // [sw_pad256 | w2]
    bf16*  Bc1    = (bf16*) alloc((size_t)256 * 1280 * 2);
    bf16*  Bc2    = (bf16*) alloc((size_t)256 * 1280 * 2);
    int*   hist   = (int*)  alloc((size_t)(kSeg + 1) * 4);
    int*   row_ptr= (int*)  alloc((size_t)(kSeg + 1) * 4);
    int*   cursor = (int*)  alloc((size_t)kSeg * 4);
    int*   srcidx = (int*)  alloc((size_t)kE * 4);
    int*   bsum   = (int*)  alloc((size_t)kScanB * 4);
    int*   boff   = (int*)  alloc((size_t)kScanB * 4);
    float* stats  = (float*)alloc(2048 * 4);
    float* scl    = (float*)alloc(1024 * 4);
    float* shf    = (float*)alloc(1024 * 4);
    float* btt    = (float*)alloc(3 * 256 * 4);
    float* pooled = (float*)alloc((size_t)kG * 256 * 4);
    float* counts = (float*)alloc(kG * 4);
    if (ws_size < off) return;  // clean absmax-fail instead of OOB crash

    const dim3 gL1((kN + 127) / 128, 4);  // l1 GEMM grid (512 thr)
    const dim3 gR((kN + 63) / 64, 4);     // rgin grid (512 thr, M-tile 64)
    const dim3 g2((kN + 63) / 64);        // GEMM2 grid (512 thr, M-tile 64)

    // ---- CSR build (parallel scan) + weight prepack ----
    hipMemsetAsync(hist, 0, (size_t)(kSeg + 1) * 4, stream);
    k_hist<<<(kE + 255) / 256, 256, 0, stream>>>(ei, et, hist);
    k_scan1<<<kScanB, 256, 0, stream>>>(hist, bsum);
    k_scan2<<<1, 1024, 0, stream>>>(bsum, boff);
    k_scan3<<<kScanB, 256, 0, stream>>>(hist, boff, row_ptr, cursor);
    k_fill<<<(kE + 255) / 256, 256, 0, stream>>>(ei, et, cursor, srcidx);

    k_bias_total<<<3, 256, 0, stream>>>(sb[0], b2[0], sb[1], b2[1], sb[2], b2[2], btt);
    k_xpad<<<(int)(((long)kN * 256 + 255) / 256), 256, 0, stream>>>(x, xb1);
    k_wtL1<<<(4 * 256 * 32 + 255) / 256, 256, 0, stream>>>(w1[0], w1tL1);
    for (int l = 1; l < 3; ++l)
        for (int r = 0; r < 4; ++r)
            k_wt_s<<<256, 256, 0, stream>>>(w1[l] + (long)r * 65536,
                                            w1t + (long)(l - 1) * 4 * 65536 + (long)r * 65536,
                                            256, 256, 256, 0);
    hipMemsetAsync(Bc0, 0, (size_t)256 * 1280 * 2, stream);
    k_wt_s<<<(11 * 256 + 255) / 256, 256, 0, stream>>>(sw[0], Bc0, 11, 256, 1280, 0);
    k_wt_s<<<1024, 256, 0, stream>>>(w2[0], Bc0, 1024, 256, 1280, 256);
    k_wt_s<<<256, 256, 0, stream>>>(sw[1], Bc1, 256, 256, 1280, 0);
    k_wt_s<<<1024, 256, 0, stream>>>(w2[1], Bc1, 1024, 256, 1280, 256);
    k_wt_s<<<256, 256, 0, stream>>>(sw[2], Bc2, 256, 256, 1280, 0);
    k_wt_s<<<1024, 256, 0, stream>>>(w2[2], Bc2, 1024, 256, 1280, 256);

    k_counts<<<(kN + 255) / 256, 256, 0, stream>>>(batch, counts);  // counts poisoned -> must init
    hipMemsetAsync(pooled, 0, (size_t)kG * 256 * 4, stream);

    // ---------------- layer 1 ----------------
    k_agg11<<<(int)(((long)kSeg * 32 + 255) / 256), 256, 0, stream>>>(x, srcidx, row_ptr, a1b);
    hipMemsetAsync(stats, 0, 2048 * 4, stream);
    k_l1gemm<<<gL1, 512, 0, stream>>>(a1b, w1tL1, h1, stats);
    k_bn_params<<<4, 256, 0, stream>>>(stats, gmm[0], btm[0], scl, shf);
    k_gemm2<false><<<g2, 512, 0, stream>>>(xb1, h1, Bc0,
                                           Pb0, kN, btt + 0, scl, shf, nullptr, nullptr);

    // ---------------- layer 2 ----------------
    hipMemsetAsync(stats, 0, 2048 * 4, stream);
    k_rgin1<<<gR, 512, 0, stream>>>(Pb0, srcidx, row_ptr, w1t, h1, stats);
    k_bn_params<<<4, 256, 0, stream>>>(stats, gmm[1], btm[1], scl, shf);
    k_gemm2<false><<<g2, 512, 0, stream>>>(Pb0, h1, Bc1,
                                           Pb1, kN, btt + 256, scl, shf, nullptr, nullptr);

    // ---------------- layer 3 (pool fused into GEMM2) ----------------
    hipMemsetAsync(stats, 0, 2048 * 4, stream);
    k_rgin1<<<gR, 512, 0, stream>>>(Pb1, srcidx, row_ptr, w1t + (size_t)4 * 65536, h1, stats);
    k_bn_params<<<4, 256, 0, stream>>>(stats, gmm[2], btm[2], scl, shf);
    k_gemm2<true><<<g2, 512, 0, stream>>>(Pb1, h1, Bc2,
                                          nullptr, kN, btt + 512, scl, shf, batch, pooled);

    // ---------------- head ----------------
    k_head<<<kG, 64, 0, stream>>>(pooled, counts, lin_w, lin_b, out);
}

// Round 11
// 1092.016 us; speedup vs baseline: 1.1315x; 1.1315x over previous
//
#include <hip/hip_runtime.h>

static const int kN = 50000;   // nodes
static const int kE = 300000;  // edges
static const int kG = 2048;    // graphs
static const int kT = 19;      // targets
static const int kSeg = kN * 4;  // CSR segments: key = dst*4 + rel
static const int kScanB = (kSeg + 256) / 256;  // 784 blocks covers kSeg+1

typedef __bf16 bf16;
typedef __bf16 bf16x8 __attribute__((ext_vector_type(8)));
typedef __bf16 bf16x4 __attribute__((ext_vector_type(4)));
typedef float  f32x4  __attribute__((ext_vector_type(4)));

// ---------------------------------------------------------------------------
// GEMM1 layers 2/3: aggregate (CSR, +self) into LDS, then MFMA vs w1t[r].
// Grid (ceil(N/64), 4=rel), 512 threads (8 waves). Proven round-9 shape.
// Layouts (m89/m91-verified): A/B idx=lane&15,k=(lane>>4)*8+j;
//                             C/D row=(lane>>4)*4+reg, col=lane&15.
// ---------------------------------------------------------------------------
__global__ __launch_bounds__(512) void k_rgin1(
    const bf16* __restrict__ Pb, const int* __restrict__ srcidx,
    const int* __restrict__ row_ptr, const bf16* __restrict__ w1t,
    bf16* __restrict__ h1, float* __restrict__ stats)
{
    __shared__ bf16 As[64][264];   // row stride 264 bf16 = 132 dwords
    const int t = threadIdx.x;
    const int r = blockIdx.y;
    const int m0 = blockIdx.x * 64;
    const int wave = t >> 6, lane = t & 63;
    const int l15 = lane & 15, lq = lane >> 4, koff = lq * 8;
    const int wn = wave * 32;

    // B pointers + first-fragment prefetch (lands during phase 1)
    const bf16* Bt = w1t + (long)r * 65536;
    const bf16* Bp[2];
#pragma unroll
    for (int j = 0; j < 2; ++j)
        Bp[j] = Bt + (long)(wn + j * 16 + l15) * 256 + koff;
    bf16x8 b0[2], b1[2];
#pragma unroll
    for (int j = 0; j < 2; ++j) b0[j] = *(const bf16x8*)(Bp[j]);

    // ---- phase 1: 8 rows per wave, headers preloaded ----
    {
        const int rbase = m0 + wave * 8;
        int i0s[8], i1s[8];
#pragma unroll
        for (int rr = 0; rr < 8; ++rr) {
            int dc = rbase + rr; if (dc >= kN) dc = kN - 1;
            int seg = dc * 4 + r;
            i0s[rr] = row_ptr[seg];
            i1s[rr] = row_ptr[seg + 1];
        }
#pragma unroll
        for (int rr = 0; rr < 8; ++rr) {
            int dc = rbase + rr; if (dc >= kN) dc = kN - 1;
            bf16x4 sv = ((const bf16x4*)(Pb + (long)dc * 256))[lane];
            f32x4 a = {(float)sv[0], (float)sv[1], (float)sv[2], (float)sv[3]};
            int i = i0s[rr], i1 = i1s[rr];
            for (; i + 1 < i1; i += 2) {
                int s0 = srcidx[i], s1 = srcidx[i + 1];
                bf16x4 v0 = ((const bf16x4*)(Pb + (long)s0 * 256))[lane];
                bf16x4 v1 = ((const bf16x4*)(Pb + (long)s1 * 256))[lane];
                a[0] += (float)v0[0] + (float)v1[0];
                a[1] += (float)v0[1] + (float)v1[1];
                a[2] += (float)v0[2] + (float)v1[2];
                a[3] += (float)v0[3] + (float)v1[3];
            }
            if (i < i1) {
                bf16x4 v0 = ((const bf16x4*)(Pb + (long)srcidx[i] * 256))[lane];
                a[0] += (float)v0[0]; a[1] += (float)v0[1];
                a[2] += (float)v0[2]; a[3] += (float)v0[3];
            }
            bf16x4 o = {(bf16)a[0], (bf16)a[1], (bf16)a[2], (bf16)a[3]};
            *(bf16x4*)&As[wave * 8 + rr][lane * 4] = o;
        }
    }
    __syncthreads();

    // ---- phase 2: MFMA from LDS, B double-buffered in regs ----
    const bf16* Ar[4];
#pragma unroll
    for (int i = 0; i < 4; ++i) Ar[i] = &As[i * 16 + l15][koff];

    f32x4 acc[4][2];
#pragma unroll
    for (int i = 0; i < 4; ++i)
#pragma unroll
        for (int j = 0; j < 2; ++j) acc[i][j] = (f32x4){0.f, 0.f, 0.f, 0.f};

#pragma unroll
    for (int kt = 0; kt < 256; kt += 32) {
        int kn = kt + 32; if (kn >= 256) kn = 0;
#pragma unroll
        for (int j = 0; j < 2; ++j) b1[j] = *(const bf16x8*)(Bp[j] + kn);
        bf16x8 a[4];
#pragma unroll
        for (int i = 0; i < 4; ++i) a[i] = *(const bf16x8*)(Ar[i] + kt);
#pragma unroll
        for (int i = 0; i < 4; ++i)
#pragma unroll
            for (int j = 0; j < 2; ++j)
                acc[i][j] = __builtin_amdgcn_mfma_f32_16x16x32_bf16(a[i], b0[j], acc[i][j], 0, 0, 0);
#pragma unroll
        for (int j = 0; j < 2; ++j) b0[j] = b1[j];
    }

    // ---- epilogue: store h1 + fused stats ----
    const int cB = r * 256;
    float sv[2] = {0, 0}, qv[2] = {0, 0};
#pragma unroll
    for (int i = 0; i < 4; ++i) {
        int rowb = m0 + i * 16 + lq * 4;
#pragma unroll
        for (int rr = 0; rr < 4; ++rr) {
            int gm = rowb + rr;
            if (gm < kN) {
#pragma unroll
                for (int j = 0; j < 2; ++j) {
                    int gn = wn + j * 16 + l15;
                    bf16 bv = (bf16)acc[i][j][rr];
                    h1[(long)gm * 1024 + cB + gn] = bv;
                    float f = (float)bv;
                    sv[j] += f; qv[j] += f * f;
                }
            }
        }
    }
#pragma unroll
    for (int j = 0; j < 2; ++j) {
        float s = sv[j], q = qv[j];
        s += __shfl_xor(s, 16); s += __shfl_xor(s, 32);
        q += __shfl_xor(q, 16); q += __shfl_xor(q, 32);
        if (lq == 0) {
            int gn = cB + wn + j * 16 + l15;
            atomicAdd(&stats[gn], s);
            atomicAdd(&stats[1024 + gn], q);
        }
    }
}

// ---------------------------------------------------------------------------
// GEMM1 layer 1: A = a1b[r] [N,32] bf16 (K=32, one MFMA step) + fused stats.
// ---------------------------------------------------------------------------
__global__ __launch_bounds__(512) void k_l1gemm(
    const bf16* __restrict__ a1b, const bf16* __restrict__ w1tL1,
    bf16* __restrict__ h1, float* __restrict__ stats)
{
    const int t = threadIdx.x;
    const int r = blockIdx.y;
    const int m0 = blockIdx.x * 128;
    const int wave = t >> 6, lane = t & 63;
    const int l15 = lane & 15, lq = lane >> 4, koff = lq * 8;
    const int wm = (wave & 1) * 64, wn = (wave >> 1) * 64;

    bf16x8 a[4], b[4];
#pragma unroll
    for (int i = 0; i < 4; ++i) {
        int gm = m0 + wm + i * 16 + l15;
        if (gm >= kN) gm = kN - 1;
        a[i] = *(const bf16x8*)(a1b + ((long)r * kN + gm) * 32 + koff);
    }
#pragma unroll
    for (int j = 0; j < 4; ++j)
        b[j] = *(const bf16x8*)(w1tL1 + (long)r * 8192 + (long)(wn + j * 16 + l15) * 32 + koff);

    f32x4 acc[4][4];
#pragma unroll
    for (int i = 0; i < 4; ++i)
#pragma unroll
        for (int j = 0; j < 4; ++j)
            acc[i][j] = __builtin_amdgcn_mfma_f32_16x16x32_bf16(a[i], b[j],
                        (f32x4){0.f, 0.f, 0.f, 0.f}, 0, 0, 0);

    const int cB = r * 256;
    float sv[4] = {0,0,0,0}, qv[4] = {0,0,0,0};
#pragma unroll
    for (int i = 0; i < 4; ++i) {
        int rowb = m0 + wm + i * 16 + lq * 4;
#pragma unroll
        for (int rr = 0; rr < 4; ++rr) {
            int gm = rowb + rr;
            if (gm < kN) {
#pragma unroll
                for (int j = 0; j < 4; ++j) {
                    int gn = wn + j * 16 + l15;
                    bf16 bv = (bf16)acc[i][j][rr];
                    h1[(long)gm * 1024 + cB + gn] = bv;
                    float f = (float)bv;
                    sv[j] += f; qv[j] += f * f;
                }
            }
        }
    }
#pragma unroll
    for (int j = 0; j < 4; ++j) {
        float s = sv[j], q = qv[j];
        s += __shfl_xor(s, 16); s += __shfl_xor(s, 32);
        q += __shfl_xor(q, 16); q += __shfl_xor(q, 32);
        if (lq == 0) {
            int gn = cB + wn + j * 16 + l15;
            atomicAdd(&stats[gn], s);
            atomicAdd(&stats[1024 + gn], q);
        }
    }
}

// ---------------------------------------------------------------------------
// GEMM2 v5 (= proven v3 K-loop, M-tile 32 for 2x grid parallelism):
// C = relu( [A1 | relu(BN(A2))] @ Bt^T + bias ).  K = CHUNKS*128 compile-time;
// A1 spans first C1 chunks (lda1 passed), A2 = h1 [*,1024] BN region.
// 256 thr (4 waves, wave n-slice 64), M-tile 32, grid ceil(M/32) = 1563
// blocks (was 782 - occupancy was grid-limited at 17%). LDS double-buffered
// As[2][32][136], one barrier pair/chunk; next-chunk A reg-prefetch over
// MFMA; B depth-2 reg prefetch; static unroll. PoolOut: atomicAdd pooled.
// ---------------------------------------------------------------------------
template<int CHUNKS, int C1, bool PoolOut>
__global__ __launch_bounds__(256) void k_gemm2(
    const bf16* __restrict__ A1, int lda1,
    const bf16* __restrict__ A2,
    const bf16* __restrict__ Bt,
    bf16* __restrict__ Cout,
    int M, const float* __restrict__ bias,
    const float* __restrict__ scl, const float* __restrict__ shf,
    const int* __restrict__ batch, float* __restrict__ pooled)
{
    constexpr int K = CHUNKS * 128;
    __shared__ bf16 As[2][32][136];
    const int t = threadIdx.x;
    const int wave = t >> 6, lane = t & 63;
    const int l15 = lane & 15, lq = lane >> 4, koff = lq * 8;
    const int wn = wave * 64;
    const int m0 = blockIdx.x * 32;

    const int srow = t >> 4;        // staging row 0..15 (+u*16, u=0..1)
    const int kg   = (t & 15) * 8;  // staging col group within chunk

    const bf16* Bp[4];
#pragma unroll
    for (int j = 0; j < 4; ++j)
        Bp[j] = Bt + (long)(wn + j * 16 + l15) * K + koff;

    f32x4 acc[2][4];
#pragma unroll
    for (int i = 0; i < 2; ++i)
#pragma unroll
        for (int j = 0; j < 4; ++j) acc[i][j] = (f32x4){0.f, 0.f, 0.f, 0.f};

    auto ld_raw = [&](int c, bf16x8* rv, float4* sf) {
#pragma unroll
        for (int u = 0; u < 2; ++u) {
            int gm = m0 + srow + u * 16; if (gm >= M) gm = M - 1;
            if (c < C1) rv[u] = *(const bf16x8*)(A1 + (long)gm * lda1 + c * 128 + kg);
            else        rv[u] = *(const bf16x8*)(A2 + (long)gm * 1024 + (c - C1) * 128 + kg);
        }
        if (c >= C1) {
            int k2 = (c - C1) * 128 + kg;
            sf[0] = *(const float4*)(scl + k2);
            sf[1] = *(const float4*)(scl + k2 + 4);
            sf[2] = *(const float4*)(shf + k2);
            sf[3] = *(const float4*)(shf + k2 + 4);
        }
    };
    auto st_lds = [&](int c, const bf16x8* rv, const float4* sf, int sel) {
        float sa[8], ta[8];
        if (c >= C1) {
            sa[0]=sf[0].x; sa[1]=sf[0].y; sa[2]=sf[0].z; sa[3]=sf[0].w;
            sa[4]=sf[1].x; sa[5]=sf[1].y; sa[6]=sf[1].z; sa[7]=sf[1].w;
            ta[0]=sf[2].x; ta[1]=sf[2].y; ta[2]=sf[2].z; ta[3]=sf[2].w;
            ta[4]=sf[3].x; ta[5]=sf[3].y; ta[6]=sf[3].z; ta[7]=sf[3].w;
        }
#pragma unroll
        for (int u = 0; u < 2; ++u) {
            bf16x8 v = rv[u];
            if (c >= C1) {
                bf16x8 o;
#pragma unroll
                for (int w = 0; w < 8; ++w)
                    o[w] = (bf16)fmaxf(0.f, fmaf((float)v[w], sa[w], ta[w]));
                v = o;
            }
            *(bf16x8*)&As[sel][srow + u * 16][kg] = v;
        }
    };

    bf16x8 rv[2]; float4 sf[4];
    ld_raw(0, rv, sf);
    bf16x8 breg[2][4];
#pragma unroll
    for (int j = 0; j < 4; ++j) breg[0][j] = *(const bf16x8*)(Bp[j]);
#pragma unroll
    for (int j = 0; j < 4; ++j) breg[1][j] = *(const bf16x8*)(Bp[j] + 32);
    st_lds(0, rv, sf, 0);
    __syncthreads();

    for (int c = 0; c < CHUNKS; ++c) {
        const int sel = c & 1;
        if (c + 1 < CHUNKS) ld_raw(c + 1, rv, sf);   // global loads fly over MFMA
#pragma unroll
        for (int ks = 0; ks < 4; ++ks) {
            bf16x8 a[2], bu[4];
#pragma unroll
            for (int i = 0; i < 2; ++i)
                a[i] = *(const bf16x8*)&As[sel][i * 16 + l15][ks * 32 + koff];
#pragma unroll
            for (int j = 0; j < 4; ++j) bu[j] = breg[ks & 1][j];
            int knext = (c * 4 + ks + 2) * 32; if (knext >= K) knext = 0;
#pragma unroll
            for (int j = 0; j < 4; ++j) breg[ks & 1][j] = *(const bf16x8*)(Bp[j] + knext);
#pragma unroll
            for (int i = 0; i < 2; ++i)
#pragma unroll
                for (int j = 0; j < 4; ++j)
                    acc[i][j] = __builtin_amdgcn_mfma_f32_16x16x32_bf16(a[i], bu[j], acc[i][j], 0, 0, 0);
        }
        if (c + 1 < CHUNKS) {
            st_lds(c + 1, rv, sf, sel ^ 1);
            __syncthreads();
        }
    }

#pragma unroll
    for (int i = 0; i < 2; ++i) {
        int rowb = m0 + i * 16 + lq * 4;
#pragma unroll
        for (int rr = 0; rr < 4; ++rr) {
            int gm = rowb + rr;
            if (gm < M) {
                int g = PoolOut ? batch[gm] : 0;
#pragma unroll
                for (int j = 0; j < 4; ++j) {
                    int gn = wn + j * 16 + l15;
                    float v = fmaxf(acc[i][j][rr] + bias[gn], 0.f);
                    if (PoolOut) atomicAdd(&pooled[(long)g * 256 + gn], v);
                    else         Cout[(long)gm * 256 + gn] = (bf16)v;
                }
            }
        }
    }
}

// ---------------------------------------------------------------------------
// CSR build
__global__ void k_hist(const int* __restrict__ ei, const int* __restrict__ et,
                       int* __restrict__ hist)
{
    int e = blockIdx.x * 256 + threadIdx.x;
    if (e >= kE) return;
    atomicAdd(&hist[ei[kE + e] * 4 + et[e]], 1);
}

__global__ void k_scan1(const int* __restrict__ hist, int* __restrict__ bsum)
{
    __shared__ int sd[256];
    int i = blockIdx.x * 256 + threadIdx.x;
    sd[threadIdx.x] = (i < kSeg) ? hist[i] : 0;
    __syncthreads();
    for (int o = 128; o > 0; o >>= 1) {
        if (threadIdx.x < o) sd[threadIdx.x] += sd[threadIdx.x + o];
        __syncthreads();
    }
    if (threadIdx.x == 0) bsum[blockIdx.x] = sd[0];
}

__global__ __launch_bounds__(1024) void k_scan2(const int* __restrict__ bsum,
                                                int* __restrict__ boff)
{
    __shared__ int sd[1024];
    int t = threadIdx.x;
    sd[t] = (t < kScanB) ? bsum[t] : 0;
    __syncthreads();
    for (int o = 1; o < 1024; o <<= 1) {
        int v = (t >= o) ? sd[t - o] : 0;
        __syncthreads();
        sd[t] += v;
        __syncthreads();
    }
    if (t < kScanB) boff[t] = (t == 0) ? 0 : sd[t - 1];
}

__global__ void k_scan3(const int* __restrict__ hist, const int* __restrict__ boff,
                        int* __restrict__ row_ptr, int* __restrict__ cursor)
{
    __shared__ int sd[256];
    int i = blockIdx.x * 256 + threadIdx.x;
    int v = (i < kSeg) ? hist[i] : 0;
    sd[threadIdx.x] = v;
    __syncthreads();
    for (int o = 1; o < 256; o <<= 1) {
        int u = (threadIdx.x >= o) ? sd[threadIdx.x - o] : 0;
        __syncthreads();
        sd[threadIdx.x] += u;
        __syncthreads();
    }
    if (i <= kSeg) {
        int excl = boff[blockIdx.x] + sd[threadIdx.x] - v;
        row_ptr[i] = excl;
        if (i < kSeg) cursor[i] = excl;
    }
}

__global__ void k_fill(const int* __restrict__ ei, const int* __restrict__ et,
                       int* __restrict__ cursor, int* __restrict__ srcidx)
{
    int e = blockIdx.x * 256 + threadIdx.x;
    if (e >= kE) return;
    int key = ei[kE + e] * 4 + et[e];
    int pos = atomicAdd(&cursor[key], 1);
    srcidx[pos] = ei[e];
}

// ---------------------------------------------------------------------------
// layer-1 aggregate: a1b[r][d][ch] = bf16( x[d][ch] + sum_src x[src][ch] ), ch<11
__global__ void k_agg11(const float* __restrict__ x, const int* __restrict__ srcidx,
                        const int* __restrict__ row_ptr, bf16* __restrict__ a1b)
{
    long gid = (long)blockIdx.x * 256 + threadIdx.x;
    if (gid >= (long)kSeg * 32) return;
    int ch  = (int)(gid & 31);
    int seg = (int)(gid >> 5);
    int d = seg >> 2, r = seg & 3;
    float acc = 0.f;
    if (ch < 11) {
        acc = x[(long)d * 11 + ch];
        int i0 = row_ptr[seg], i1 = row_ptr[seg + 1];
        for (int i = i0; i < i1; ++i) acc += x[(long)srcidx[i] * 11 + ch];
    }
    a1b[((long)r * kN + d) * 32 + ch] = (bf16)acc;
}

// x [N,11] fp32 -> xb1 [N,128] bf16 zero-padded (chunk-aligned for k_gemm2)
__global__ void k_xpad(const float* __restrict__ x, bf16* __restrict__ xb1)
{
    long gid = (long)blockIdx.x * 256 + threadIdx.x;
    if (gid >= (long)kN * 128) return;
    int c = (int)(gid & 127); long d = gid >> 7;
    xb1[gid] = (c < 11) ? (bf16)x[d * 11 + c] : (bf16)0.f;
}

// weight transpose-pack: in [K,N] fp32 -> out[n*ldout + coff + k] bf16
__global__ void k_wt_s(const float* __restrict__ in, bf16* __restrict__ out,
                       int K, int N, int ldout, int coff)
{
    int i = blockIdx.x * 256 + threadIdx.x;
    if (i >= K * N) return;
    int n = i / K, k = i - n * K;
    out[(long)n * ldout + coff + k] = (bf16)in[(long)k * N + n];
}

// layer-1 w1 pack: [4][11][256] fp32 -> [4][256][32] bf16 zero-padded
__global__ void k_wtL1(const float* __restrict__ w1, bf16* __restrict__ out)
{
    int i = blockIdx.x * 256 + threadIdx.x;
    if (i >= 4 * 256 * 32) return;
    int r = i >> 13, rem = i & 8191, n = rem >> 5, k = rem & 31;
    out[i] = (k < 11) ? (bf16)w1[(long)r * 11 * 256 + (long)k * 256 + n] : (bf16)0.f;
}

__global__ void k_bn_params(const float* __restrict__ stats,
                            const float* __restrict__ g, const float* __restrict__ bt,
                            float* __restrict__ scl, float* __restrict__ shf)
{
    int c = blockIdx.x * 256 + threadIdx.x;  // < 1024
    const float invN = 1.0f / (float)kN;
    float mu  = stats[c] * invN;
    float var = stats[1024 + c] * invN - mu * mu;
    float sc  = g[c] * rsqrtf(var + 1e-5f);
    scl[c] = sc;
    shf[c] = bt[c] - mu * sc;
}

__global__ void k_bias_total(const float* sb0, const float* b20,
                             const float* sb1, const float* b21,
                             const float* sb2, const float* b22,
                             float* __restrict__ btt)
{
    int l = blockIdx.x, j = threadIdx.x;
    const float* sb = (l == 0) ? sb0 : (l == 1) ? sb1 : sb2;
    const float* b2 = (l == 0) ? b20 : (l == 1) ? b21 : b22;
    float v = sb[j];
#pragma unroll
    for (int r = 0; r < 4; ++r) v += b2[r * 256 + j];
    btt[l * 256 + j] = v;
}

__global__ void k_counts(const int* __restrict__ batch, float* __restrict__ counts)
{
    int v = blockIdx.x * 256 + threadIdx.x;
    if (v < kN) atomicAdd(&counts[batch[v]], 1.0f);
}

__global__ __launch_bounds__(64) void k_head(const float* __restrict__ pooled,
                                             const float* __restrict__ counts,
                                             const float* __restrict__ lw,
                                             const float* __restrict__ lb,
                                             float* __restrict__ out)
{
    int g = blockIdx.x;
    int l = threadIdx.x;
    float inv = 1.0f / fmaxf(counts[g], 1.0f);
    float acc[kT];
#pragma unroll
    for (int t = 0; t < kT; ++t) acc[t] = 0.f;
    for (int k = l; k < 256; k += 64) {
        float p = pooled[((long)g << 8) + k] * inv;
#pragma unroll
        for (int t = 0; t < kT; ++t) acc[t] = fmaf(p, lw[k * kT + t], acc[t]);
    }
#pragma unroll
    for (int off = 32; off > 0; off >>= 1)
#pragma unroll
        for (int t = 0; t < kT; ++t) acc[t] += __shfl_down(acc[t], off);
    if (l == 0) {
#pragma unroll
        for (int t = 0; t < kT; ++t) out[(long)g * kT + t] = acc[t] + lb[t];
    }
}

// ---------------------------------------------------------------------------
extern "C" void kernel_launch(void* const* d_in, const int* in_sizes, int n_in,
                              void* d_out, int out_size, void* d_ws, size_t ws_size,
                              hipStream_t stream)
{
    const float* x     = (const float*)d_in[0];
    const int*   ei    = (const int*)d_in[1];
    const int*   et    = (const int*)d_in[2];
    const int*   batch = (const int*)d_in[3];

    const float *sw[3], *sb[3], *w1[3], *gmm[3], *btm[3], *w2[3], *b2[3];
    for (int l = 0; l < 3; ++l) {
        int b = 4 + l * 8;
        sw[l]  = (const float*)d_in[b + 0];
        sb[l]  = (const float*)d_in[b + 1];
        w1[l]  = (const float*)d_in[b + 2];
        // b+3 = b1 (cancels inside BatchNorm)
        gmm[l] = (const float*)d_in[b + 4];
        btm[l] = (const float*)d_in[b + 5];
        w2[l]  = (const float*)d_in[b + 6];
        b2[l]  = (const float*)d_in[b + 7];
    }
    const float* lin_w = (const float*)d_in[28];
    const float* lin_b = (const float*)d_in[29];
    float* out = (float*)d_out;
    (void)in_sizes; (void)n_in; (void)out_size;

    // ---- workspace (~186 MB) ----
    char* wsb = (char*)d_ws;
    size_t off = 0;
    auto alloc = [&](size_t bytes) { void* p = wsb + off; off = (off + bytes + 255) & ~(size_t)255; return p; };
    bf16*  Pb0    = (bf16*) alloc((size_t)kN * 256 * 2);
    bf16*  Pb1    = (bf16*) alloc((size_t)kN * 256 * 2);
    bf16*  h1     = (bf16*) alloc((size_t)kN * 1024 * 2);
    bf16*  a1b    = (bf16*) alloc((size_t)4 * kN * 32 * 2);
    bf16*  xb1    = (bf16*) alloc((size_t)kN * 128 * 2);        // padded to 128
    bf16*  w1t    = (bf16*) alloc((size_t)2 * 4 * 65536 * 2);   // layers 2,3
    bf16*  w1tL1  = (bf16*) alloc((size_t)4 * 256 * 32 * 2);
    bf16*  Bc0    = (bf16*) alloc((size_t)256 * 1152 * 2);      // [sw_pad128 | w2]
    bf16*  Bc1    = (bf16*) alloc((size_t)256 * 1280 * 2);
    bf16*  Bc2    = (bf16*) alloc((size_t)256 * 1280 * 2);
    int*   hist   = (int*)  alloc((size_t)(kSeg + 1) * 4);
    int*   row_ptr= (int*)  alloc((size_t)(kSeg + 1) * 4);
    int*   cursor = (int*)  alloc((size_t)kSeg * 4);
    int*   srcidx = (int*)  alloc((size_t)kE * 4);
    int*   bsum   = (int*)  alloc((size_t)kScanB * 4);
    int*   boff   = (int*)  alloc((size_t)kScanB * 4);
    float* stats  = (float*)alloc(2048 * 4);
    float* scl    = (float*)alloc(1024 * 4);
    float* shf    = (float*)alloc(1024 * 4);
    float* btt    = (float*)alloc(3 * 256 * 4);
    float* pooled = (float*)alloc((size_t)kG * 256 * 4);
    float* counts = (float*)alloc(kG * 4);
    if (ws_size < off) return;  // clean absmax-fail instead of OOB crash

    const dim3 gL1((kN + 127) / 128, 4);  // l1 GEMM grid (512 thr)
    const dim3 gR((kN + 63) / 64, 4);     // rgin grid (512 thr, M-tile 64)
    const dim3 g2((kN + 31) / 32);        // GEMM2 grid (256 thr, M-tile 32, 1563 blocks)

    // ---- CSR build (parallel scan) + weight prepack ----
    hipMemsetAsync(hist, 0, (size_t)(kSeg + 1) * 4, stream);
    k_hist<<<(kE + 255) / 256, 256, 0, stream>>>(ei, et, hist);
    k_scan1<<<kScanB, 256, 0, stream>>>(hist, bsum);
    k_scan2<<<1, 1024, 0, stream>>>(bsum, boff);
    k_scan3<<<kScanB, 256, 0, stream>>>(hist, boff, row_ptr, cursor);
    k_fill<<<(kE + 255) / 256, 256, 0, stream>>>(ei, et, cursor, srcidx);

    k_bias_total<<<3, 256, 0, stream>>>(sb[0], b2[0], sb[1], b2[1], sb[2], b2[2], btt);
    k_xpad<<<(int)(((long)kN * 128 + 255) / 256), 256, 0, stream>>>(x, xb1);
    k_wtL1<<<(4 * 256 * 32 + 255) / 256, 256, 0, stream>>>(w1[0], w1tL1);
    for (int l = 1; l < 3; ++l)
        for (int r = 0; r < 4; ++r)
            k_wt_s<<<256, 256, 0, stream>>>(w1[l] + (long)r * 65536,
                                            w1t + (long)(l - 1) * 4 * 65536 + (long)r * 65536,
                                            256, 256, 256, 0);
    hipMemsetAsync(Bc0, 0, (size_t)256 * 1152 * 2, stream);
    k_wt_s<<<(11 * 256 + 255) / 256, 256, 0, stream>>>(sw[0], Bc0, 11, 256, 1152, 0);
    k_wt_s<<<1024, 256, 0, stream>>>(w2[0], Bc0, 1024, 256, 1152, 128);
    k_wt_s<<<256, 256, 0, stream>>>(sw[1], Bc1, 256, 256, 1280, 0);
    k_wt_s<<<1024, 256, 0, stream>>>(w2[1], Bc1, 1024, 256, 1280, 256);
    k_wt_s<<<256, 256, 0, stream>>>(sw[2], Bc2, 256, 256, 1280, 0);
    k_wt_s<<<1024, 256, 0, stream>>>(w2[2], Bc2, 1024, 256, 1280, 256);

    k_counts<<<(kN + 255) / 256, 256, 0, stream>>>(batch, counts);  // counts poisoned -> must init
    hipMemsetAsync(pooled, 0, (size_t)kG * 256 * 4, stream);

    // ---------------- layer 1 ----------------
    k_agg11<<<(int)(((long)kSeg * 32 + 255) / 256), 256, 0, stream>>>(x, srcidx, row_ptr, a1b);
    hipMemsetAsync(stats, 0, 2048 * 4, stream);
    k_l1gemm<<<gL1, 512, 0, stream>>>(a1b, w1tL1, h1, stats);
    k_bn_params<<<4, 256, 0, stream>>>(stats, gmm[0], btm[0], scl, shf);
    k_gemm2<9, 1, false><<<g2, 256, 0, stream>>>(xb1, 128, h1, Bc0,
                                                 Pb0, kN, btt + 0, scl, shf, nullptr, nullptr);

    // ---------------- layer 2 ----------------
    hipMemsetAsync(stats, 0, 2048 * 4, stream);
    k_rgin1<<<gR, 512, 0, stream>>>(Pb0, srcidx, row_ptr, w1t, h1, stats);
    k_bn_params<<<4, 256, 0, stream>>>(stats, gmm[1], btm[1], scl, shf);
    k_gemm2<10, 2, false><<<g2, 256, 0, stream>>>(Pb0, 256, h1, Bc1,
                                                  Pb1, kN, btt + 256, scl, shf, nullptr, nullptr);

    // ---------------- layer 3 (pool fused into GEMM2) ----------------
    hipMemsetAsync(stats, 0, 2048 * 4, stream);
    k_rgin1<<<gR, 512, 0, stream>>>(Pb1, srcidx, row_ptr, w1t + (size_t)4 * 65536, h1, stats);
    k_bn_params<<<4, 256, 0, stream>>>(stats, gmm[2], btm[2], scl, shf);
    k_gemm2<10, 2, true><<<g2, 256, 0, stream>>>(Pb1, 256, h1, Bc2,
                                                 nullptr, kN, btt + 512, scl, shf, batch, pooled);

    // ---------------- head ----------------
    k_head<<<kG, 64, 0, stream>>>(pooled, counts, lin_w, lin_b, out);
}